// Round 5
// baseline (449.135 us; speedup 1.0000x reference)
//
#include <hip/hip_runtime.h>
#include <math.h>

// YOLO head activation, v3: persistent single-wave blocks, double-buffered
// cross-tile pipeline with counted vmcnt waits (copy-like issue pattern).
//
// v1 (TPB=128, 3-phase, ~102us kernel) and v2 (TPB=64 + global_load_lds,
// ~104us kernel) both serialize per wave: load-drain(vmcnt 0) -> compute
// (no mem issue) -> store. Kernel ran at 5.25 TB/s vs 6.29 TB/s measured
// copy ceiling. v3 removes the serialization: each block is ONE wave that
// grid-strides over 64-segment tiles with 2 LDS buffers:
//
//   issue DMA(t+1) -> buf^1            (22 global_load_lds, width 16)
//   s_waitcnt vmcnt(44)                 // tile-t loads done; newer ops =
//                                       // 22 stores(t-1) + 22 loads(t+1)
//   compute tile t in buf (in place)    // exp/sigmoid/softmax-sum
//   store tile t (22 float4 stores, scaling class slots)
//
// Loads for tile t are issued a full iteration ahead; vmcnt never drains to
// 0 in steady state; loads+stores are continuously in flight (T3/T4).
// No barriers anywhere (single wave per block). LDS 43KB -> 3 blocks/CU;
// 44 outstanding 1KB vmem ops per wave x 3 waves = ~132KB in flight per CU,
// far above the ~9KB Little's-law minimum for fair-share HBM BW.

#define SEG 85
#define NCELLS 49
#define TPB 64
#define WORDS_PER_TILE (TPB * SEG)              // 5440
#define F4_PER_TILE (WORDS_PER_TILE / 4)        // 1360
#define FULL_SWEEPS (F4_PER_TILE / TPB)         // 21
#define TAIL (F4_PER_TILE - FULL_SWEEPS * TPB)  // 16
#define PERSIST_BLOCKS 768                      // 3 per CU exactly

#define GLOAD_LDS16(g, l)                                   \
  __builtin_amdgcn_global_load_lds(                         \
      (const __attribute__((address_space(1))) void*)(g),   \
      (__attribute__((address_space(3))) void*)(l), 16, 0, 0)

__global__ __launch_bounds__(TPB) void yolo_act_kernel(
    const float* __restrict__ in, float* __restrict__ out, int ntiles) {
  __shared__ __align__(16) float lds[2][WORDS_PER_TILE];
  __shared__ float inv_s[2][TPB + 1];

  const int tid = threadIdx.x;

  int t = blockIdx.x;
  if (t >= ntiles) return;

  // ---- prologue: issue DMA for first tile into buf 0 (22 vm events) ----
  {
    const float* gsrc = in + (long long)t * WORDS_PER_TILE;
    #pragma unroll
    for (int it = 0; it < FULL_SWEEPS; ++it)
      GLOAD_LDS16(gsrc + (it * TPB + tid) * 4, &lds[0][it * TPB * 4]);
    if (tid < TAIL)
      GLOAD_LDS16(gsrc + (FULL_SWEEPS * TPB + tid) * 4,
                  &lds[0][FULL_SWEEPS * TPB * 4]);
  }

  int buf = 0;
  bool has_prev = false;

  while (true) {
    const int tnext = t + gridDim.x;
    const bool has_next = (tnext < ntiles);

    // ---- prefetch: issue DMA for tile t+1 into the other buffer ----
    if (has_next) {
      const float* gsrc = in + (long long)tnext * WORDS_PER_TILE;
      float* l = &lds[buf ^ 1][0];
      #pragma unroll
      for (int it = 0; it < FULL_SWEEPS; ++it)
        GLOAD_LDS16(gsrc + (it * TPB + tid) * 4, l + it * TPB * 4);
      if (tid < TAIL)
        GLOAD_LDS16(gsrc + (FULL_SWEEPS * TPB + tid) * 4,
                    l + FULL_SWEEPS * TPB * 4);
    }

    // ---- counted wait for tile t's loads (in-order vmcnt retire) ----
    // newer-than-tile-t vm ops: 22 stores(t-1) if has_prev, 22 loads(t+1)
    // if has_next. Wait leaves exactly those in flight.
    if (has_prev && has_next)
      asm volatile("s_waitcnt vmcnt(44)" ::: "memory");
    else if (has_prev || has_next)
      asm volatile("s_waitcnt vmcnt(22)" ::: "memory");
    else
      asm volatile("s_waitcnt vmcnt(0)" ::: "memory");
    __builtin_amdgcn_sched_barrier(0);

    // ---- compute: thread tid activates segment tid of tile t in place ----
    {
      const int seg_global = t * TPB + tid;
      const int cell = seg_global % NCELLS;
      float* p = &lds[buf][tid * SEG];  // stride 85: 2-way bank alias, free
      if (cell != NCELLS - 1) {
        float s0 = 0.f, s1 = 0.f, s2 = 0.f, s3 = 0.f;
        #pragma unroll
        for (int i = 5; i < SEG; i += 4) {  // 20 iters, classes 5..84
          float e0 = __expf(p[i + 0]);
          float e1 = __expf(p[i + 1]);
          float e2 = __expf(p[i + 2]);
          float e3 = __expf(p[i + 3]);
          p[i + 0] = e0; p[i + 1] = e1; p[i + 2] = e2; p[i + 3] = e3;
          s0 += e0; s1 += e1; s2 += e2; s3 += e3;
        }
        p[0] = 1.f / (1.f + __expf(-p[0]));
        p[1] = 1.f / (1.f + __expf(-p[1]));
        p[4] = 1.f / (1.f + __expf(-p[4]));
        inv_s[buf][tid] = 1.f / ((s0 + s1) + (s2 + s3));
      } else {
        inv_s[buf][tid] = -1.f;  // passthrough cell: scale disabled
      }
      if (tid == 0) inv_s[buf][TPB] = -1.f;  // guard for seg0+1 peek
    }

    // ---- store: LDS -> global, coalesced float4, scale class slots ----
    // 22 global_store_dwordx4 issues (21 full sweeps + 16-lane tail).
    {
      float4* __restrict__ gdst =
          (float4*)(out + (long long)t * WORDS_PER_TILE);
      const float4* lsrc = (const float4*)&lds[buf][0];
      const float* inv = &inv_s[buf][0];
      #pragma unroll
      for (int it = 0; it <= FULL_SWEEPS; ++it) {
        if (it == FULL_SWEEPS && tid >= TAIL) break;
        const int k = tid + it * TPB;
        float4 v = lsrc[k];
        const int w = k * 4;
        const int seg0 = w / SEG;            // compiler magic-mul
        const int off0 = w - seg0 * SEG;
        const float sc0 = inv[seg0];
        const float sc1 = inv[seg0 + 1];
        float r[4] = {v.x, v.y, v.z, v.w};
        #pragma unroll
        for (int j = 0; j < 4; ++j) {
          const int o = off0 + j;
          const bool cross = (o >= SEG);
          const float sc = cross ? sc1 : sc0;
          const int off = cross ? (o - SEG) : o;
          if (off >= 5 && sc > 0.f) r[j] *= sc;
        }
        v.x = r[0]; v.y = r[1]; v.z = r[2]; v.w = r[3];
        gdst[k] = v;
      }
    }

    if (!has_next) break;
    t = tnext;
    buf ^= 1;
    has_prev = true;
  }
}

extern "C" void kernel_launch(void* const* d_in, const int* in_sizes, int n_in,
                              void* d_out, int out_size, void* d_ws, size_t ws_size,
                              hipStream_t stream) {
  const float* in = (const float*)d_in[0];
  float* out = (float*)d_out;
  const int nseg = in_sizes[0] / SEG;        // 802816
  const int ntiles = nseg / TPB;             // 12544, exact
  const int grid = (ntiles < PERSIST_BLOCKS) ? ntiles : PERSIST_BLOCKS;
  yolo_act_kernel<<<grid, TPB, 0, stream>>>(in, out, ntiles);
}